// Round 10
// baseline (400.038 us; speedup 1.0000x reference)
//
#include <hip/hip_runtime.h>

#define NN 100000
#define EE 3200000
#define NF 256
#define NH 128
#define NC 16
#define NBKT 391       // buckets of 256 dst nodes: ceil(100000/256)
#define BSZ 256        // nodes per bucket
#define BCAP 9600      // staging capacity per bucket (mean 8192, +15.5 sigma)
#define CHUNK 2048     // edges per k_bucket block (2048: 36 KB LDS -> 4 blocks/CU)

typedef __bf16 bf16;
typedef bf16 bf16x2 __attribute__((ext_vector_type(2)));
typedef bf16 bf16x4 __attribute__((ext_vector_type(4)));
typedef bf16 bf16x8 __attribute__((ext_vector_type(8)));
typedef float f32x2 __attribute__((ext_vector_type(2)));
typedef float f32x4 __attribute__((ext_vector_type(4)));

// ---------------- prep: W1 convert + cursor init + edge pad (one launch) ----------------

__global__ void k_prep(const float* __restrict__ W1, bf16* __restrict__ W1T,
                       int* __restrict__ bucket_cursor, int2* __restrict__ edges) {
    int b = blockIdx.x, t = threadIdx.x;
    if (b < 128) {
        int i = b * 256 + t;                 // 32768 elems, W1 is [NF][NH]
        int k = i >> 7, n = i & 127;
        W1T[n * NF + k] = (bf16)W1[i];       // W1T: [NH][NF]
    } else {
        for (int i = t; i < NBKT; i += 256) bucket_cursor[i] = i * BCAP;
        if (t < 32) edges[EE + t] = make_int2(0, 0);   // 32-record pad for spmm overrun
    }
}

// ---------------- CSR build: bucket partition (LDS-binned contiguous writes) ----------------

__global__ __launch_bounds__(512) void k_bucket(const int* __restrict__ src,
                                                const int* __restrict__ dst,
                                                const float* __restrict__ ew,
                                                int* __restrict__ bucket_cursor,
                                                int2* __restrict__ staged) {
    __shared__ int2 recs[CHUNK];              // 16 KB
    __shared__ int sdst[CHUNK];               // 8 KB
    __shared__ unsigned short bkt[CHUNK];     // 4 KB
    __shared__ int cnt[NBKT], start[NBKT + 1], cur[NBKT], gbase[NBKT];
    __shared__ int sc[512];
    int t = threadIdx.x;
    int base = blockIdx.x * CHUNK;
    int n = EE - base; if (n > CHUNK) n = CHUNK;
    if (t < NBKT) cnt[t] = 0;
    __syncthreads();
    for (int i = t; i < n; i += 512) {
        int d = dst[base + i];
        sdst[i] = d;
        atomicAdd(&cnt[d >> 8], 1);
    }
    __syncthreads();
    sc[t] = (t < NBKT) ? cnt[t] : 0;
    __syncthreads();
    for (int off = 1; off < 512; off <<= 1) {
        int v = (t >= off) ? sc[t - off] : 0;
        __syncthreads();
        sc[t] += v;
        __syncthreads();
    }
    if (t < NBKT) { start[t] = sc[t] - cnt[t]; cur[t] = sc[t] - cnt[t]; }
    if (t == 0) start[NBKT] = sc[511];
    __syncthreads();
    for (int i = t; i < n; i += 512) {
        int d = sdst[i];
        int b = d >> 8;
        int p = atomicAdd(&cur[b], 1);
        recs[p] = make_int2(src[base + i] | ((d & 255) << 17), __float_as_int(ew[base + i]));
        bkt[p] = (unsigned short)b;
    }
    __syncthreads();
    if (t < NBKT) gbase[t] = atomicAdd(&bucket_cursor[t], start[t + 1] - start[t]);
    __syncthreads();
    for (int i = t; i < n; i += 512) {
        int b = bkt[i];
        staged[gbase[b] + (i - start[b])] = recs[i];
    }
}

// Exclusive scan of per-bucket counts -> global base of each bucket in edges[].
__global__ void k_bscan(const int* __restrict__ bucket_cursor,
                        int* __restrict__ bucket_base, int* __restrict__ row_off) {
    __shared__ int s[512];
    int t = threadIdx.x;
    int v = (t < NBKT) ? (bucket_cursor[t] - t * BCAP) : 0;
    s[t] = v;
    __syncthreads();
    for (int off = 1; off < 512; off <<= 1) {
        int x = (t >= off) ? s[t - off] : 0;
        __syncthreads();
        s[t] += x;
        __syncthreads();
    }
    if (t < NBKT) bucket_base[t] = s[t] - v;
    if (t == 0) { bucket_base[NBKT] = EE; row_off[NN] = EE; }
}

// ---------------- fused: k_sort (391 blocks) || k_gemm1 (1564 half-feature blocks) ----------
// v2 of the fusion: both bodies shrunk to a 32.8 KB LDS union so the fused
// kernel runs 3-4 blocks/CU (24-32 waves, was 2 blocks/16 waves at 80 KB) --
// the gemm1 half was latency-bound on L3 x-reads at 16 waves.
//   sort: 2-pass (re-reads staged from global for the scatter; drops the
//         76.8 KB lrec cache; +25.6 MB coalesced reads ~ 5 us of BW).
//   gemm1: feature-split -- each block stages 64 of W1T's 128 rows (32 KB)
//         and computes a 128-row x 64-feature output half; acc restructured
//         per-ct to keep VGPR ~65 (fits launch_bounds(512,6) cap of 85).

union SortGemmSmem {
    struct {
        int lcnt[BSZ], lstart[BSZ], lcur[BSZ];   // 3 KB
    } s;
    unsigned short sW[64 * NF];                  // 32 KB
};

__device__ __forceinline__ void sort_body(SortGemmSmem& u, int b,
                                          const int2* __restrict__ staged,
                                          const int* __restrict__ bucket_cursor,
                                          const int* __restrict__ bucket_base,
                                          int* __restrict__ row_off,
                                          int2* __restrict__ edges) {
    int t = threadIdx.x;
    int n = bucket_cursor[b] - b * BCAP;
    int gb = bucket_base[b];
    const int2* sp = staged + (size_t)b * BCAP;
    if (t < BSZ) u.s.lcnt[t] = 0;
    __syncthreads();
    for (int i = t; i < n; i += 512) {
        int sx = sp[i].x;                        // pass A: count per node
        atomicAdd(&u.s.lcnt[sx >> 17], 1);
    }
    __syncthreads();
    if (t < BSZ) u.s.lstart[t] = u.s.lcnt[t];
    __syncthreads();
    for (int off = 1; off < BSZ; off <<= 1) {
        int v = 0;
        if (t < BSZ && t >= off) v = u.s.lstart[t - off];
        __syncthreads();
        if (t < BSZ) u.s.lstart[t] += v;
        __syncthreads();
    }
    if (t < BSZ) {
        int ex = u.s.lstart[t] - u.s.lcnt[t];    // exclusive within-bucket start
        u.s.lcur[t] = ex;
        int node = (b << 8) + t;
        if (node < NN) row_off[node] = gb + ex;
    }
    __syncthreads();
    for (int i = t; i < n; i += 512) {           // pass B: re-read + scatter
        int2 r = sp[i];
        int d = r.x >> 17;
        int p = atomicAdd(&u.s.lcur[d], 1);
        edges[gb + p] = make_int2(r.x & 0x1FFFF, r.y);
    }
}

__device__ __forceinline__ void gemm1_body(SortGemmSmem& u, int gid,
                                           const float* __restrict__ x,
                                           const bf16* __restrict__ W1T,
                                           unsigned char* __restrict__ h0q) {
    int t = threadIdx.x;
    int lane = t & 63;
    int wid = t >> 6;      // 0..7
    int m = lane & 15;     // x row within 16-tile
    int kg = lane >> 4;    // k-group 0..3
    int half = gid & 1;    // feature half: rows [half*64, half*64+64) of W1T
    int row = (gid >> 1) * 128 + wid * 16 + m;
    bool in = (row < NN);
    const float* xr = x + (size_t)row * NF;
    const bf16* wbase = W1T + (size_t)half * 64 * NF;

    // stage 64 W1T rows -> LDS via async DMA; dest linear, XOR swizzle on SOURCE.
#pragma unroll
    for (int it = 0; it < 4; it++) {
        int cid = t + it * 512;                        // 2048 chunks of 16 B
        int n = cid >> 5, ch = cid & 31;
        const bf16* srcp = wbase + (size_t)n * NF + ((ch ^ (n & 7)) << 3);
        __builtin_amdgcn_global_load_lds(
            (const __attribute__((address_space(1))) void*)srcp,
            (__attribute__((address_space(3))) void*)&u.sW[cid << 3],
            16, 0, 0);
    }

    // x loads: 16 dwordx4 in flight under the staging DMA
    bf16x8 a[8];
#pragma unroll
    for (int kt = 0; kt < 8; kt++) {
        int k0 = kt * 32 + kg * 8;
        float4 uu = in ? *(const float4*)(xr + k0)     : make_float4(0.f, 0.f, 0.f, 0.f);
        float4 vv = in ? *(const float4*)(xr + k0 + 4) : make_float4(0.f, 0.f, 0.f, 0.f);
        bf16x8 av = { (bf16)uu.x, (bf16)uu.y, (bf16)uu.z, (bf16)uu.w,
                      (bf16)vv.x, (bf16)vv.y, (bf16)vv.z, (bf16)vv.w };
        a[kt] = av;
    }
    __syncthreads();   // drains vmcnt(0): staging + x loads

    unsigned char* rp = h0q + (size_t)row * NH + half * 64 + kg * 4;
#pragma unroll
    for (int ct = 0; ct < 4; ct++) {
        f32x4 acc = {};
        int brow = ct * 16 + m;                  // W feature row (A operand), local
        const unsigned short* bp = u.sW + brow * NF;
        int sw = brow & 7;
#pragma unroll
        for (int kt = 0; kt < 8; kt++) {
            int ch = kt * 4 + kg;
            bf16x8 b = *(const bf16x8*)(bp + ((ch ^ sw) << 3));
            // A = W fragment, B = x fragment: D[feat][xrow]
            acc = __builtin_amdgcn_mfma_f32_16x16x32_bf16(b, a[kt], acc, 0, 0, 0);
        }
        // D: col = lane&15 = own x row, reg = feature -> 1 dword fp8 store
        if (in) {
            unsigned lo = (unsigned)__builtin_amdgcn_cvt_pk_fp8_f32(acc[0], acc[1], 0, false);
            unsigned pk = (unsigned)__builtin_amdgcn_cvt_pk_fp8_f32(acc[2], acc[3], lo, true);
            *(unsigned*)(rp + ct * 16) = pk;
        }
    }
}

__global__ __launch_bounds__(512, 6) void k_sortgemm1(const int2* __restrict__ staged,
                                                      const int* __restrict__ bucket_cursor,
                                                      const int* __restrict__ bucket_base,
                                                      int* __restrict__ row_off,
                                                      int2* __restrict__ edges,
                                                      const float* __restrict__ x,
                                                      const bf16* __restrict__ W1T,
                                                      unsigned char* __restrict__ h0q) {
    __shared__ SortGemmSmem u;
    int bid = blockIdx.x;                        // 1955 = 5 * 391 blocks
    int r5 = bid % 5;
    if (r5 == 0) sort_body(u, bid / 5, staged, bucket_cursor, bucket_base, row_off, edges);
    else         gemm1_body(u, (bid / 5) * 4 + r5 - 1, x, W1T, h0q);
}

// ---------------- spmm1 + gemm2 fused: g = relu(A @ h0 + b1) @ W2 ----------------
// UNCHANGED from the measured-best r9 version (74.7 us). v6's sW2-LDS and
// v7's record prefetch both regressed and are reverted for good: the gather
// loop is issue-balanced -- do not add per-iteration instructions.

__global__ __launch_bounds__(256) void k_spmm1g(const int* __restrict__ row_off,
                                                const int2* __restrict__ edges,
                                                const unsigned char* __restrict__ h0q,
                                                const float* __restrict__ b1,
                                                const float* __restrict__ W2,
                                                bf16* __restrict__ g) {
    __shared__ float hs[4][NH];                    // 2 KB
    int wid = __builtin_amdgcn_readfirstlane(threadIdx.x >> 6);
    int node = blockIdx.x * 4 + wid;               // wave-uniform, always < NN
    int lane = threadIdx.x & 63;
    int lq = lane & 31;
    bool hhi = lane >= 32;                         // loop-invariant half mask
    int kg = lane >> 4, c = lane & 15;

    // W2 column slice (compiler re-loads from L1 per node; measured faster
    // than LDS staging -- W2 is 8 KB, L1-resident)
    float w2r[32];
#pragma unroll
    for (int j = 0; j < 32; j++) w2r[j] = W2[(kg * 32 + j) * NC + c];

    int s = row_off[node], e = row_off[node + 1];  // uniform -> s_load
    unsigned loff = (unsigned)lq * 4u;             // byte offset within row

    float a0[2] = {0.f, 0.f}, a1[2] = {0.f, 0.f};
    float a2[2] = {0.f, 0.f}, a3[2] = {0.f, 0.f};

    for (int i = s; i < e; i += 16) {
        int2 q[16];
#pragma unroll
        for (int j = 0; j < 16; j++) q[j] = edges[i + j];   // uniform -> s_load
        unsigned so[8]; float wo[8];
#pragma unroll
        for (int j = 0; j < 8; j++) {
            bool v0 = (i + 2 * j)     < e;                   // scalar cmp
            bool v1 = (i + 2 * j + 1) < e;
            unsigned s0 = v0 ? (unsigned)q[2 * j].x : 0u;    // s_cselect
            unsigned s1 = v1 ? (unsigned)q[2 * j + 1].x : 0u;
            float w0 = v0 ? __int_as_float(q[2 * j].y) : 0.f;
            float w1 = v1 ? __int_as_float(q[2 * j + 1].y) : 0.f;
            so[j] = hhi ? s1 : s0;                           // v_cndmask
            wo[j] = hhi ? w1 : w0;                           // v_cndmask
        }
        unsigned dv[8];
#pragma unroll
        for (int j = 0; j < 8; j++) {
            unsigned off = (so[j] << 7) + loff;              // 1 VALU, 24-bit range
            dv[j] = *(const unsigned*)(h0q + off);           // 8 gathers in flight
        }
#pragma unroll
        for (int j = 0; j < 8; j++) {
            f32x2 f01 = __builtin_amdgcn_cvt_pk_f32_fp8(dv[j], false);
            f32x2 f23 = __builtin_amdgcn_cvt_pk_f32_fp8(dv[j], true);
            int p = j & 1;
            a0[p] += wo[j] * f01[0];
            a1[p] += wo[j] * f01[1];
            a2[p] += wo[j] * f23[0];
            a3[p] += wo[j] * f23[1];
        }
    }
    float t0 = a0[0] + a0[1];
    float t1 = a1[0] + a1[1];
    float t2 = a2[0] + a2[1];
    float t3 = a3[0] + a3[1];
    // combine the two halves (each summed a disjoint edge subset)
    t0 += __shfl_xor(t0, 32);
    t1 += __shfl_xor(t1, 32);
    t2 += __shfl_xor(t2, 32);
    t3 += __shfl_xor(t3, 32);

    // h values (all lanes have them; channels 4lq..4lq+3)
    float4 bv = ((const float4*)b1)[lq];
    float r0 = fmaxf(t0 + bv.x, 0.f);
    float r1 = fmaxf(t1 + bv.y, 0.f);
    float r2 = fmaxf(t2 + bv.z, 0.f);
    float r3 = fmaxf(t3 + bv.w, 0.f);
    if (!hhi) *(float4*)&hs[wid][lq * 4] = make_float4(r0, r1, r2, r3);
    // same-wave write->read: LDS pipe is in-order per wave; compiler keeps
    // program order (may-alias) and inserts lgkmcnt before use.
    const float* hp = &hs[wid][kg * 32];
    float p = 0.f;
#pragma unroll
    for (int j = 0; j < 32; j++) p += hp[j] * w2r[j];
    p += __shfl_xor(p, 16);                        // combine kg pairs
    p += __shfl_xor(p, 32);
    if (lane < 16) g[(size_t)node * NC + lane] = (bf16)p;
}

// ---------------- spmm2 + bias + log_softmax fused ----------------
// UNCHANGED (v2): one wave per node; 8-lane groups, dword = 2 bf16 channels,
// 4 VMEM per 16 edges; shfl-tree reduce + lanes 0-7 softmax; float2 stores.

__global__ __launch_bounds__(256) void k_spmm2(const int* __restrict__ row_off,
                                               const int2* __restrict__ edges,
                                               const bf16* __restrict__ g,
                                               const float* __restrict__ b2,
                                               float* __restrict__ out) {
    int node = (blockIdx.x * 256 + threadIdx.x) >> 6;  // 4 nodes per block
    int lane = threadIdx.x & 63;
    int grp = lane >> 3, l = lane & 7;
    int s = row_off[node], e = row_off[node + 1];
    const char* gb = (const char*)g;
    unsigned coff = (unsigned)l * 4u;                  // channel-pair byte offset

    float a0 = 0.f, a1 = 0.f;
    for (int i = s; i < e; i += 16) {
        int i0 = i + grp, i1 = i0 + 8;
        int2 r0 = edges[i0];                           // 8-addr coalesced
        int2 r1 = edges[i1];                           // <= e+15: pad covers
        bool v0 = i0 < e, v1 = i1 < e;
        unsigned s0 = v0 ? (unsigned)r0.x : 0u;        // v_cndmask
        float    w0 = v0 ? __int_as_float(r0.y) : 0.f;
        unsigned s1 = v1 ? (unsigned)r1.x : 0u;
        float    w1 = v1 ? __int_as_float(r1.y) : 0.f;
        unsigned d0 = *(const unsigned*)(gb + ((s0 << 5) + coff));
        unsigned d1 = *(const unsigned*)(gb + ((s1 << 5) + coff));
        a0 += w0 * __int_as_float(d0 << 16);
        a1 += w0 * __int_as_float(d0 & 0xffff0000u);
        a0 += w1 * __int_as_float(d1 << 16);
        a1 += w1 * __int_as_float(d1 & 0xffff0000u);
    }
    // sum across the 8 groups (lanes l, l+8, ..., l+56)
    a0 += __shfl_xor(a0, 8);  a1 += __shfl_xor(a1, 8);
    a0 += __shfl_xor(a0, 16); a1 += __shfl_xor(a1, 16);
    a0 += __shfl_xor(a0, 32); a1 += __shfl_xor(a1, 32);
    // lanes 0-7 hold channels {2l, 2l+1}
    float2 bv = ((const float2*)b2)[l];
    a0 += bv.x; a1 += bv.y;
    float m = fmaxf(a0, a1);
    m = fmaxf(m, __shfl_xor(m, 1));
    m = fmaxf(m, __shfl_xor(m, 2));
    m = fmaxf(m, __shfl_xor(m, 4));
    float e0 = __expf(a0 - m), e1 = __expf(a1 - m);
    float sum = e0 + e1;
    sum += __shfl_xor(sum, 1);
    sum += __shfl_xor(sum, 2);
    sum += __shfl_xor(sum, 4);
    float ls = __logf(sum);
    if (l == lane && lane < 8) {   // lanes 0-7
        float2 o = { a0 - m - ls, a1 - m - ls };
        *(float2*)(out + (size_t)node * NC + 2 * l) = o;
    }
}

// ---------------- launch ----------------

extern "C" void kernel_launch(void* const* d_in, const int* in_sizes, int n_in,
                              void* d_out, int out_size, void* d_ws, size_t ws_size,
                              hipStream_t stream) {
    const float* x  = (const float*)d_in[0];
    const float* W1 = (const float*)d_in[1];
    const float* b1 = (const float*)d_in[2];
    const float* W2 = (const float*)d_in[3];
    const float* b2 = (const float*)d_in[4];
    const float* ew = (const float*)d_in[5];
    const int* src  = (const int*)d_in[6];
    const int* dst  = (const int*)d_in[7];
    float* out = (float*)d_out;

    char* ws = (char*)d_ws;
    unsigned char* h0q = (unsigned char*)(ws + 0);  // NN*NH = 12,800,000 (fp8)
    bf16*  g       = (bf16*)(ws + 12800000);       // NN*NC*2 = 3,200,000
    int*   row_off = (int*)(ws + 16000000);        // (NN+1)*4 = 400,004
    int*   bucket_cursor = (int*)(ws + 16400016);  // 1,564
    int*   bucket_base   = (int*)(ws + 16401584);  // 1,568
    int2*  edges   = (int2*)(ws + 16403168);       // EE*8 + 256 pad = 25,600,256
    bf16*  W1T     = (bf16*)(ws + 42003424);       // 65,536
    int2*  staged  = (int2*)(ws + 42068960);       // NBKT*BCAP*8 = 30,028,800
    // staged must NOT alias h0q: gemm1 writes h0q while sort reads staged.

    // prep (cvtW1 + cursor init + edge pad) then CSR bucket pass + scan
    k_prep<<<129, 256, 0, stream>>>(W1, W1T, bucket_cursor, edges);
    k_bucket<<<(EE + CHUNK - 1) / CHUNK, 512, 0, stream>>>(src, dst, ew, bucket_cursor, staged);
    k_bscan<<<1, 512, 0, stream>>>(bucket_cursor, bucket_base, row_off);

    // sort || gemm1 (independent; fused for overlap): 391 + 1564 = 1955 blocks
    k_sortgemm1<<<1955, 512, 0, stream>>>(staged, bucket_cursor, bucket_base,
                                          row_off, edges, x, W1T, h0q);

    // layer 1 spmm + layer 2 dense (fused)
    k_spmm1g<<<NN / 4, 256, 0, stream>>>(row_off, edges, h0q, b1, W2, g);

    // layer 2 spmm + log_softmax
    k_spmm2<<<NN / 4, 256, 0, stream>>>(row_off, edges, g, b2, out);
}

// Round 11
// 363.607 us; speedup vs baseline: 1.1002x; 1.1002x over previous
//
#include <hip/hip_runtime.h>

#define NN 100000
#define EE 3200000
#define NF 256
#define NH 128
#define NC 16
#define NBKT 391       // buckets of 256 dst nodes: ceil(100000/256)
#define BSZ 256        // nodes per bucket
#define BCAP 9600      // staging capacity per bucket (mean 8192, +15.5 sigma)
#define CHUNK 4096     // edges per bucket-pass block (r9-proven)

typedef __bf16 bf16;
typedef bf16 bf16x2 __attribute__((ext_vector_type(2)));
typedef bf16 bf16x4 __attribute__((ext_vector_type(4)));
typedef bf16 bf16x8 __attribute__((ext_vector_type(8)));
typedef float f32x2 __attribute__((ext_vector_type(2)));
typedef float f32x4 __attribute__((ext_vector_type(4)));

// ---------------- prep: W1 convert + cursor init + edge pad (one launch) ----------------

__global__ void k_prep(const float* __restrict__ W1, bf16* __restrict__ W1T,
                       int* __restrict__ bucket_cursor, int2* __restrict__ edges) {
    int b = blockIdx.x, t = threadIdx.x;
    if (b < 128) {
        int i = b * 256 + t;                 // 32768 elems, W1 is [NF][NH]
        int k = i >> 7, n = i & 127;
        W1T[n * NF + k] = (bf16)W1[i];       // W1T: [NH][NF]
    } else {
        for (int i = t; i < NBKT; i += 256) bucket_cursor[i] = i * BCAP;
        if (t < 32) edges[EE + t] = make_int2(0, 0);   // 32-record pad for spmm overrun
    }
}

// Exclusive scan of per-bucket counts -> global base of each bucket in edges[].
__global__ void k_bscan(const int* __restrict__ bucket_cursor,
                        int* __restrict__ bucket_base, int* __restrict__ row_off) {
    __shared__ int s[512];
    int t = threadIdx.x;
    int v = (t < NBKT) ? (bucket_cursor[t] - t * BCAP) : 0;
    s[t] = v;
    __syncthreads();
    for (int off = 1; off < 512; off <<= 1) {
        int x = (t >= off) ? s[t - off] : 0;
        __syncthreads();
        s[t] += x;
        __syncthreads();
    }
    if (t < NBKT) bucket_base[t] = s[t] - v;
    if (t == 0) { bucket_base[NBKT] = EE; row_off[NN] = EE; }
}

// ---------------- fused: k_bucket (782 blocks) || k_gemm1 (782 blocks) ----------------
// r11 chain reorder: r9 paired sort||gemm1 and ran bucket ALONE (~45 us);
// bucket||gemm1 is equally legal (bucket: src/dst/ew; gemm1: W1T/x -- fully
// independent) and leaves the CHEAPER pass (sort, ~35 us LDS-cached) to run
// alone. Old: bucket + max(sort,gemm1) ~ 117; new: max(bucket,gemm1) + sort
// ~ 103. Both bodies are byte-identical to their r9-proven versions; no new
// traffic (r10's feature-split regression taught: never add bytes for waves).

union BucketGemmSmem {
    struct {
        int2 recs[CHUNK];                     // 32 KB
        int sdst[CHUNK];                      // 16 KB
        unsigned short bkt[CHUNK];            // 8 KB
        int cnt[NBKT], start[NBKT + 1], cur[NBKT], gbase[NBKT];
        int sc[512];                          // ~2 KB   (total ~64.4 KB)
    } b;
    unsigned short sW[NH * NF];               // 64 KB
};

__device__ __forceinline__ void bucket_body(BucketGemmSmem& u, int cid,
                                            const int* __restrict__ src,
                                            const int* __restrict__ dst,
                                            const float* __restrict__ ew,
                                            int* __restrict__ bucket_cursor,
                                            int2* __restrict__ staged) {
    int t = threadIdx.x;
    int base = cid * CHUNK;
    int n = EE - base; if (n > CHUNK) n = CHUNK;
    if (t < NBKT) u.b.cnt[t] = 0;
    __syncthreads();
    for (int i = t; i < n; i += 512) {
        int d = dst[base + i];
        u.b.sdst[i] = d;
        atomicAdd(&u.b.cnt[d >> 8], 1);
    }
    __syncthreads();
    u.b.sc[t] = (t < NBKT) ? u.b.cnt[t] : 0;
    __syncthreads();
    for (int off = 1; off < 512; off <<= 1) {
        int v = (t >= off) ? u.b.sc[t - off] : 0;
        __syncthreads();
        u.b.sc[t] += v;
        __syncthreads();
    }
    if (t < NBKT) { u.b.start[t] = u.b.sc[t] - u.b.cnt[t]; u.b.cur[t] = u.b.sc[t] - u.b.cnt[t]; }
    if (t == 0) u.b.start[NBKT] = u.b.sc[511];
    __syncthreads();
    for (int i = t; i < n; i += 512) {
        int d = u.b.sdst[i];
        int b = d >> 8;
        int p = atomicAdd(&u.b.cur[b], 1);
        u.b.recs[p] = make_int2(src[base + i] | ((d & 255) << 17), __float_as_int(ew[base + i]));
        u.b.bkt[p] = (unsigned short)b;
    }
    __syncthreads();
    if (t < NBKT) u.b.gbase[t] = atomicAdd(&bucket_cursor[t], u.b.start[t + 1] - u.b.start[t]);
    __syncthreads();
    for (int i = t; i < n; i += 512) {
        int b = u.b.bkt[i];
        staged[u.b.gbase[b] + (i - u.b.start[b])] = u.b.recs[i];
    }
}

__device__ __forceinline__ void gemm1_body(BucketGemmSmem& u, int gid,
                                           const float* __restrict__ x,
                                           const bf16* __restrict__ W1T,
                                           unsigned char* __restrict__ h0q) {
    int t = threadIdx.x;
    int lane = t & 63;
    int wid = t >> 6;      // 0..7
    int m = lane & 15;     // x row within 16-tile
    int kg = lane >> 4;    // k-group 0..3
    int row = gid * 128 + wid * 16 + m;
    bool in = (row < NN);
    const float* xr = x + (size_t)row * NF;

    // stage W1T -> LDS via async DMA; dest linear, XOR swizzle on the SOURCE.
#pragma unroll
    for (int it = 0; it < 8; it++) {
        int cid = t + it * 512;                        // 4096 chunks of 16 B
        int n = cid >> 5, ch = cid & 31;
        const bf16* srcp = W1T + (size_t)n * NF + ((ch ^ (n & 7)) << 3);
        __builtin_amdgcn_global_load_lds(
            (const __attribute__((address_space(1))) void*)srcp,
            (__attribute__((address_space(3))) void*)&u.sW[cid << 3],
            16, 0, 0);
    }

    // x loads: 16 dwordx4 in flight under the staging DMA
    bf16x8 a[8];
#pragma unroll
    for (int kt = 0; kt < 8; kt++) {
        int k0 = kt * 32 + kg * 8;
        float4 uu = in ? *(const float4*)(xr + k0)     : make_float4(0.f, 0.f, 0.f, 0.f);
        float4 vv = in ? *(const float4*)(xr + k0 + 4) : make_float4(0.f, 0.f, 0.f, 0.f);
        bf16x8 av = { (bf16)uu.x, (bf16)uu.y, (bf16)uu.z, (bf16)uu.w,
                      (bf16)vv.x, (bf16)vv.y, (bf16)vv.z, (bf16)vv.w };
        a[kt] = av;
    }
    __syncthreads();   // drains vmcnt(0): staging + x loads

    f32x4 acc[8] = {};
#pragma unroll
    for (int ct = 0; ct < 8; ct++) {
        int brow = ct * 16 + m;                  // W feature row (A operand)
        const unsigned short* bp = u.sW + brow * NF;
        int sw = brow & 7;
#pragma unroll
        for (int kt = 0; kt < 8; kt++) {
            int ch = kt * 4 + kg;
            bf16x8 b = *(const bf16x8*)(bp + ((ch ^ sw) << 3));
            // A = W fragment, B = x fragment: D[feat][xrow]
            acc[ct] = __builtin_amdgcn_mfma_f32_16x16x32_bf16(b, a[kt], acc[ct], 0, 0, 0);
        }
    }

    // D: col = lane&15 = own x row, reg = feature -> 1 dword fp8 store per ct.
    if (in) {
        unsigned char* rp = h0q + (size_t)row * NH + kg * 4;
#pragma unroll
        for (int ct = 0; ct < 8; ct++) {
            unsigned lo = (unsigned)__builtin_amdgcn_cvt_pk_fp8_f32(
                              acc[ct][0], acc[ct][1], 0, false);
            unsigned pk = (unsigned)__builtin_amdgcn_cvt_pk_fp8_f32(
                              acc[ct][2], acc[ct][3], lo, true);
            *(unsigned*)(rp + ct * 16) = pk;
        }
    }
}

__global__ __launch_bounds__(512, 4) void k_bucketgemm1(const int* __restrict__ src,
                                                        const int* __restrict__ dst,
                                                        const float* __restrict__ ew,
                                                        int* __restrict__ bucket_cursor,
                                                        int2* __restrict__ staged,
                                                        const float* __restrict__ x,
                                                        const bf16* __restrict__ W1T,
                                                        unsigned char* __restrict__ h0q) {
    __shared__ BucketGemmSmem u;
    int bid = blockIdx.x;                        // 1564 = 2 * 782 blocks
    if (bid & 1) gemm1_body(u, bid >> 1, x, W1T, h0q);
    else         bucket_body(u, bid >> 1, src, dst, ew, bucket_cursor, staged);
}

// ---------------- sort: one block per bucket, LDS counting sort (r9-proven) ----------------

__global__ __launch_bounds__(512) void k_sort(const int2* __restrict__ staged,
                                              const int* __restrict__ bucket_cursor,
                                              const int* __restrict__ bucket_base,
                                              int* __restrict__ row_off,
                                              int2* __restrict__ edges) {
    __shared__ int2 lrec[BCAP];               // 76.8 KB
    __shared__ int lcnt[BSZ], lstart[BSZ], lcur[BSZ];
    int t = threadIdx.x;
    int b = blockIdx.x;
    int n = bucket_cursor[b] - b * BCAP;
    int gb = bucket_base[b];
    const int2* sp = staged + (size_t)b * BCAP;
    if (t < BSZ) lcnt[t] = 0;
    __syncthreads();
    for (int i = t; i < n; i += 512) {
        int2 r = sp[i];
        lrec[i] = r;
        atomicAdd(&lcnt[r.x >> 17], 1);
    }
    __syncthreads();
    if (t < BSZ) lstart[t] = lcnt[t];
    __syncthreads();
    for (int off = 1; off < BSZ; off <<= 1) {
        int v = 0;
        if (t < BSZ && t >= off) v = lstart[t - off];
        __syncthreads();
        if (t < BSZ) lstart[t] += v;
        __syncthreads();
    }
    if (t < BSZ) {
        int ex = lstart[t] - lcnt[t];        // exclusive within-bucket start
        lcur[t] = ex;
        int node = (b << 8) + t;
        if (node < NN) row_off[node] = gb + ex;
    }
    __syncthreads();
    for (int i = t; i < n; i += 512) {
        int2 r = lrec[i];
        int d = r.x >> 17;
        int p = atomicAdd(&lcur[d], 1);
        edges[gb + p] = make_int2(r.x & 0x1FFFF, r.y);
    }
}

// ---------------- spmm1 + gemm2 fused: g = relu(A @ h0 + b1) @ W2 ----------------
// UNCHANGED from the measured-best r9 version (74.7 us). v6's sW2-LDS and
// v7's record prefetch both regressed and are reverted for good: the gather
// loop is issue-balanced -- do not add per-iteration instructions.

__global__ __launch_bounds__(256) void k_spmm1g(const int* __restrict__ row_off,
                                                const int2* __restrict__ edges,
                                                const unsigned char* __restrict__ h0q,
                                                const float* __restrict__ b1,
                                                const float* __restrict__ W2,
                                                bf16* __restrict__ g) {
    __shared__ float hs[4][NH];                    // 2 KB
    int wid = __builtin_amdgcn_readfirstlane(threadIdx.x >> 6);
    int node = blockIdx.x * 4 + wid;               // wave-uniform, always < NN
    int lane = threadIdx.x & 63;
    int lq = lane & 31;
    bool hhi = lane >= 32;                         // loop-invariant half mask
    int kg = lane >> 4, c = lane & 15;

    // W2 column slice (compiler re-loads from L1 per node; measured faster
    // than LDS staging -- W2 is 8 KB, L1-resident)
    float w2r[32];
#pragma unroll
    for (int j = 0; j < 32; j++) w2r[j] = W2[(kg * 32 + j) * NC + c];

    int s = row_off[node], e = row_off[node + 1];  // uniform -> s_load
    unsigned loff = (unsigned)lq * 4u;             // byte offset within row

    float a0[2] = {0.f, 0.f}, a1[2] = {0.f, 0.f};
    float a2[2] = {0.f, 0.f}, a3[2] = {0.f, 0.f};

    for (int i = s; i < e; i += 16) {
        int2 q[16];
#pragma unroll
        for (int j = 0; j < 16; j++) q[j] = edges[i + j];   // uniform -> s_load
        unsigned so[8]; float wo[8];
#pragma unroll
        for (int j = 0; j < 8; j++) {
            bool v0 = (i + 2 * j)     < e;                   // scalar cmp
            bool v1 = (i + 2 * j + 1) < e;
            unsigned s0 = v0 ? (unsigned)q[2 * j].x : 0u;    // s_cselect
            unsigned s1 = v1 ? (unsigned)q[2 * j + 1].x : 0u;
            float w0 = v0 ? __int_as_float(q[2 * j].y) : 0.f;
            float w1 = v1 ? __int_as_float(q[2 * j + 1].y) : 0.f;
            so[j] = hhi ? s1 : s0;                           // v_cndmask
            wo[j] = hhi ? w1 : w0;                           // v_cndmask
        }
        unsigned dv[8];
#pragma unroll
        for (int j = 0; j < 8; j++) {
            unsigned off = (so[j] << 7) + loff;              // 1 VALU, 24-bit range
            dv[j] = *(const unsigned*)(h0q + off);           // 8 gathers in flight
        }
#pragma unroll
        for (int j = 0; j < 8; j++) {
            f32x2 f01 = __builtin_amdgcn_cvt_pk_f32_fp8(dv[j], false);
            f32x2 f23 = __builtin_amdgcn_cvt_pk_f32_fp8(dv[j], true);
            int p = j & 1;
            a0[p] += wo[j] * f01[0];
            a1[p] += wo[j] * f01[1];
            a2[p] += wo[j] * f23[0];
            a3[p] += wo[j] * f23[1];
        }
    }
    float t0 = a0[0] + a0[1];
    float t1 = a1[0] + a1[1];
    float t2 = a2[0] + a2[1];
    float t3 = a3[0] + a3[1];
    // combine the two halves (each summed a disjoint edge subset)
    t0 += __shfl_xor(t0, 32);
    t1 += __shfl_xor(t1, 32);
    t2 += __shfl_xor(t2, 32);
    t3 += __shfl_xor(t3, 32);

    // h values (all lanes have them; channels 4lq..4lq+3)
    float4 bv = ((const float4*)b1)[lq];
    float r0 = fmaxf(t0 + bv.x, 0.f);
    float r1 = fmaxf(t1 + bv.y, 0.f);
    float r2 = fmaxf(t2 + bv.z, 0.f);
    float r3 = fmaxf(t3 + bv.w, 0.f);
    if (!hhi) *(float4*)&hs[wid][lq * 4] = make_float4(r0, r1, r2, r3);
    // same-wave write->read: LDS pipe is in-order per wave; compiler keeps
    // program order (may-alias) and inserts lgkmcnt before use.
    const float* hp = &hs[wid][kg * 32];
    float p = 0.f;
#pragma unroll
    for (int j = 0; j < 32; j++) p += hp[j] * w2r[j];
    p += __shfl_xor(p, 16);                        // combine kg pairs
    p += __shfl_xor(p, 32);
    if (lane < 16) g[(size_t)node * NC + lane] = (bf16)p;
}

// ---------------- spmm2 + bias + log_softmax fused ----------------
// UNCHANGED (v2): one wave per node; 8-lane groups, dword = 2 bf16 channels,
// 4 VMEM per 16 edges; shfl-tree reduce + lanes 0-7 softmax; float2 stores.

__global__ __launch_bounds__(256) void k_spmm2(const int* __restrict__ row_off,
                                               const int2* __restrict__ edges,
                                               const bf16* __restrict__ g,
                                               const float* __restrict__ b2,
                                               float* __restrict__ out) {
    int node = (blockIdx.x * 256 + threadIdx.x) >> 6;  // 4 nodes per block
    int lane = threadIdx.x & 63;
    int grp = lane >> 3, l = lane & 7;
    int s = row_off[node], e = row_off[node + 1];
    const char* gb = (const char*)g;
    unsigned coff = (unsigned)l * 4u;                  // channel-pair byte offset

    float a0 = 0.f, a1 = 0.f;
    for (int i = s; i < e; i += 16) {
        int i0 = i + grp, i1 = i0 + 8;
        int2 r0 = edges[i0];                           // 8-addr coalesced
        int2 r1 = edges[i1];                           // <= e+15: pad covers
        bool v0 = i0 < e, v1 = i1 < e;
        unsigned s0 = v0 ? (unsigned)r0.x : 0u;        // v_cndmask
        float    w0 = v0 ? __int_as_float(r0.y) : 0.f;
        unsigned s1 = v1 ? (unsigned)r1.x : 0u;
        float    w1 = v1 ? __int_as_float(r1.y) : 0.f;
        unsigned d0 = *(const unsigned*)(gb + ((s0 << 5) + coff));
        unsigned d1 = *(const unsigned*)(gb + ((s1 << 5) + coff));
        a0 += w0 * __int_as_float(d0 << 16);
        a1 += w0 * __int_as_float(d0 & 0xffff0000u);
        a0 += w1 * __int_as_float(d1 << 16);
        a1 += w1 * __int_as_float(d1 & 0xffff0000u);
    }
    // sum across the 8 groups (lanes l, l+8, ..., l+56)
    a0 += __shfl_xor(a0, 8);  a1 += __shfl_xor(a1, 8);
    a0 += __shfl_xor(a0, 16); a1 += __shfl_xor(a1, 16);
    a0 += __shfl_xor(a0, 32); a1 += __shfl_xor(a1, 32);
    // lanes 0-7 hold channels {2l, 2l+1}
    float2 bv = ((const float2*)b2)[l];
    a0 += bv.x; a1 += bv.y;
    float m = fmaxf(a0, a1);
    m = fmaxf(m, __shfl_xor(m, 1));
    m = fmaxf(m, __shfl_xor(m, 2));
    m = fmaxf(m, __shfl_xor(m, 4));
    float e0 = __expf(a0 - m), e1 = __expf(a1 - m);
    float sum = e0 + e1;
    sum += __shfl_xor(sum, 1);
    sum += __shfl_xor(sum, 2);
    sum += __shfl_xor(sum, 4);
    float ls = __logf(sum);
    if (l == lane && lane < 8) {   // lanes 0-7
        float2 o = { a0 - m - ls, a1 - m - ls };
        *(float2*)(out + (size_t)node * NC + 2 * l) = o;
    }
}

// ---------------- launch ----------------

extern "C" void kernel_launch(void* const* d_in, const int* in_sizes, int n_in,
                              void* d_out, int out_size, void* d_ws, size_t ws_size,
                              hipStream_t stream) {
    const float* x  = (const float*)d_in[0];
    const float* W1 = (const float*)d_in[1];
    const float* b1 = (const float*)d_in[2];
    const float* W2 = (const float*)d_in[3];
    const float* b2 = (const float*)d_in[4];
    const float* ew = (const float*)d_in[5];
    const int* src  = (const int*)d_in[6];
    const int* dst  = (const int*)d_in[7];
    float* out = (float*)d_out;

    char* ws = (char*)d_ws;
    unsigned char* h0q = (unsigned char*)(ws + 0);  // NN*NH = 12,800,000 (fp8)
    bf16*  g       = (bf16*)(ws + 12800000);       // NN*NC*2 = 3,200,000
    int*   row_off = (int*)(ws + 16000000);        // (NN+1)*4 = 400,004
    int*   bucket_cursor = (int*)(ws + 16400016);  // 1,564
    int*   bucket_base   = (int*)(ws + 16401584);  // 1,568
    int2*  edges   = (int2*)(ws + 16403168);       // EE*8 + 256 pad = 25,600,256
    bf16*  W1T     = (bf16*)(ws + 42003424);       // 65,536
    int2*  staged  = (int2*)(ws + 42068960);       // NBKT*BCAP*8 = 30,028,800
    // staged must NOT alias h0q: gemm1 writes h0q while bucket writes staged.

    // prep: cvtW1 + cursor init + edge pad
    k_prep<<<129, 256, 0, stream>>>(W1, W1T, bucket_cursor, edges);

    // bucket || gemm1 (independent; fused for overlap): 782 + 782 = 1564 blocks
    k_bucketgemm1<<<1564, 512, 0, stream>>>(src, dst, ew, bucket_cursor, staged,
                                            x, W1T, h0q);
    k_bscan<<<1, 512, 0, stream>>>(bucket_cursor, bucket_base, row_off);
    k_sort<<<NBKT, 512, 0, stream>>>(staged, bucket_cursor, bucket_base, row_off, edges);

    // layer 1 spmm + layer 2 dense (fused)
    k_spmm1g<<<NN / 4, 256, 0, stream>>>(row_off, edges, h0q, b1, W2, g);

    // layer 2 spmm + log_softmax
    k_spmm2<<<NN / 4, 256, 0, stream>>>(row_off, edges, g, b2, out);
}